// Round 5
// baseline (631.540 us; speedup 1.0000x reference)
//
#include <hip/hip_runtime.h>

// SimpleRetention R5: B=131072 batches of 14x14 fp32, 4 sequential 7x7
// chunks with carried state r.
// Lessons R1-R4: ONLY wave-lane-contiguous global load/store instructions
// give ~1x HBM traffic (scattered per-thread accesses amplify 3-6x). So:
//  - input: async global_load_lds (lane-contiguous global, linear LDS),
//  - compute: lane-private LDS row -> regs -> o written over dead x slots
//    (same-wave DS ops are in-order -> no barriers needed in 1-wave blocks),
//  - output: conflict-free LDS reads + lane-contiguous global stores.
// 24.5KB LDS/block -> 6 blocks/CU; grid 2048 = all resident, phases drift.

#define CS 7
#define NT 64
#define HW 98   // words per half per batch

typedef __attribute__((address_space(1))) const unsigned int GCU;
typedef __attribute__((address_space(3))) unsigned int LU;

__device__ __forceinline__ void gl_lds_dw(const float* gp, float* lp) {
    __builtin_amdgcn_global_load_lds((GCU*)gp, (LU*)lp, 4, 0, 0);
}

// Issue 98 async dword global->LDS loads for half H of this block's 64
// batches. Global addresses lane-contiguous; LDS fills linearly:
// slot idx = k*64+lane = bl*98+e, global word = bl*196 + H*98 + e.
template <int H>
__device__ __forceinline__ void stage_half(const float* __restrict__ Xb,
                                           float* __restrict__ xs, int lane) {
    int e  = lane;             // idx % 98 (lane < 98 at k=0)
    int gw = H * HW + lane;    // bl*196 + H*98 + e
#pragma unroll
    for (int k = 0; k < HW; ++k) {
        gl_lds_dw(Xb + gw, xs + k * NT);
        int ne = e + NT;
        int w = ne >= HW;
        e  = w ? ne - HW : ne;
        gw += w ? (NT + HW) : NT;   // wrap: +64+98 ; else +64
    }
}

// Coalesced store of half H: LDS read linear (conflict-free), global
// stores lane-contiguous.
template <int H>
__device__ __forceinline__ void store_half(float* __restrict__ Ob,
                                           const float* __restrict__ xs,
                                           int lane) {
    int e  = lane;
    int gw = H * HW + lane;
#pragma unroll
    for (int k = 0; k < HW; ++k) {
        Ob[gw] = xs[k * NT + lane];
        int ne = e + NT;
        int w = ne >= HW;
        e  = w ? ne - HW : ne;
        gw += w ? (NT + HW) : NT;
    }
}

template <int C>
__device__ __forceinline__ void chunk(const float* xrow, float* xw, float r[49],
                                      const float* __restrict__ WQ,
                                      const float* __restrict__ WK,
                                      const float* __restrict__ WV,
                                      const float* __restrict__ Dm) {
    constexpr int CO = (C & 1) * CS;        // col offset within half-row
    constexpr int RO = (C >> 1) * CS;       // global row offset (for D)
    const float* wq = WQ + C * 49;          // wave-uniform -> s_load
    const float* wk = WK + C * 49;
    const float* wv = WV + C * 49;

    // x chunk: 49 LDS reads from this lane's private row (then slots dead)
    float x[49];
#pragma unroll
    for (int i = 0; i < CS; ++i)
#pragma unroll
        for (int j = 0; j < CS; ++j)
            x[i * CS + j] = xrow[i * 14 + CO + j];

    // K = x @ Wk, V = x @ Wv
    float K[49], V[49];
#pragma unroll
    for (int j = 0; j < CS; ++j) {
        float wck[CS], wcv[CS];
#pragma unroll
        for (int k = 0; k < CS; ++k) {
            wck[k] = wk[k * CS + j];
            wcv[k] = wv[k * CS + j];
        }
#pragma unroll
        for (int i = 0; i < CS; ++i) {
            float ak = 0.f, av = 0.f;
#pragma unroll
            for (int k = 0; k < CS; ++k) {
                ak = fmaf(x[i * CS + k], wck[k], ak);
                av = fmaf(x[i * CS + k], wcv[k], av);
            }
            K[i * CS + j] = ak;
            V[i * CS + j] = av;
        }
    }

    // per output row d: q -> s -> cross(r_prev) -> o -> write over x slots
#pragma unroll
    for (int d = 0; d < CS; ++d) {
        const float ev = (d == 0) ? 0.2f : (d == 1) ? 0.04f : (d == 2) ? 0.008f
                        : (d == 3) ? 0.0016f : (d == 4) ? 3.2e-4f
                        : (d == 5) ? 6.4e-5f : 1.28e-5f;
        float q[CS];
#pragma unroll
        for (int j = 0; j < CS; ++j) {
            float a = 0.f;
#pragma unroll
            for (int k = 0; k < CS; ++k)
                a = fmaf(x[d * CS + k], wq[k * CS + j], a);
            q[j] = a;
        }
        float s[CS];
#pragma unroll
        for (int k = 0; k < CS; ++k) {
            float a = 0.f;
#pragma unroll
            for (int j = 0; j < CS; ++j) a = fmaf(q[j], K[k * CS + j], a);
            s[k] = a * Dm[(RO + d) * 14 + CO + k];   // uniform -> s_load
        }
        float o[CS];
#pragma unroll
        for (int v = 0; v < CS; ++v) {
            float a = 0.f;
#pragma unroll
            for (int j = 0; j < CS; ++j) a = fmaf(q[j], r[j * CS + v], a);
            o[v] = ev * a;
        }
#pragma unroll
        for (int k = 0; k < CS; ++k)
#pragma unroll
            for (int v = 0; v < CS; ++v)
                o[v] = fmaf(s[k], V[k * CS + v], o[v]);
#pragma unroll
        for (int v = 0; v < CS; ++v)
            xw[d * 14 + CO + v] = o[v];   // lane-private slot, x[d] dead
    }

    // r += K^T V
#pragma unroll
    for (int dd = 0; dd < CS; ++dd)
#pragma unroll
        for (int v = 0; v < CS; ++v) {
            float a = r[dd * CS + v];
#pragma unroll
            for (int k = 0; k < CS; ++k)
                a = fmaf(K[k * CS + dd], V[k * CS + v], a);
            r[dd * CS + v] = a;
        }
}

__global__ __launch_bounds__(NT, 2) void retention_kernel(
    const float* __restrict__ X, const float* __restrict__ WQ,
    const float* __restrict__ WK, const float* __restrict__ WV,
    const float* __restrict__ Dm, float* __restrict__ Out) {
    __shared__ float xs[NT * HW];   // 25088 B -> 6 blocks/CU
    const int lane = threadIdx.x;
    const size_t blk = (size_t)blockIdx.x * NT;
    const float* Xb = X + blk * 196;
    float*       Ob = Out + blk * 196;

    float r[49];
#pragma unroll
    for (int i = 0; i < 49; ++i) r[i] = 0.f;

    stage_half<0>(Xb, xs, lane);

    const float* xrow = xs + lane * HW;  // this lane's private row
    float*       xw   = xs + lane * HW;

    // ---- half 0 (chunks 0,1)
    asm volatile("s_waitcnt vmcnt(0)" ::: "memory");   // gload data landed
    chunk<0>(xrow, xw, r, WQ, WK, WV, Dm);
    chunk<1>(xrow, xw, r, WQ, WK, WV, Dm);
    store_half<0>(Ob, xs, lane);
    asm volatile("s_waitcnt lgkmcnt(0)" ::: "memory"); // store reads done
    // ---- half 1 (chunks 2,3)
    stage_half<1>(Xb, xs, lane);
    asm volatile("s_waitcnt vmcnt(0)" ::: "memory");
    chunk<2>(xrow, xw, r, WQ, WK, WV, Dm);
    chunk<3>(xrow, xw, r, WQ, WK, WV, Dm);
    store_half<1>(Ob, xs, lane);
}

extern "C" void kernel_launch(void* const* d_in, const int* in_sizes, int n_in,
                              void* d_out, int out_size, void* d_ws, size_t ws_size,
                              hipStream_t stream) {
    const float* X  = (const float*)d_in[0];
    const float* WQ = (const float*)d_in[1];
    const float* WK = (const float*)d_in[2];
    const float* WV = (const float*)d_in[3];
    const float* Dm = (const float*)d_in[4];
    float* Out = (float*)d_out;

    int B = in_sizes[0] / 196;   // 131072, divisible by 64
    int grid = B / NT;
    retention_kernel<<<grid, NT, 0, stream>>>(X, WQ, WK, WV, Dm, Out);
}

// Round 6
// 443.482 us; speedup vs baseline: 1.4241x; 1.4241x over previous
//
#include <hip/hip_runtime.h>

// SimpleRetention R6: B=131072 batches of 14x14 fp32, 4 sequential 7x7
// chunks with carried state r.
// Structure (lessons R1-R5): the ONLY ~1x-traffic I/O is wave-lane-contiguous
// vector load/store (R2). R2's cost was latency (rolled staging, divides).
// R6: 1-wave blocks (64 batches, 25KB LDS -> 6 blocks/CU, ZERO barriers:
// same-wave DS ops are in-order), staging fully unrolled through registers:
// 49 independent float2 loads -> one latency exposure per phase; LDS slots
// linear (static imm offsets, sequential banks). Store symmetric. Compute
// reads lane-private stride-98 row (2 lanes/bank = free).

#define CS 7
#define NT 64
#define F2PH 49   // float2 per batch per half
#define LDSW 98   // words per batch in LDS

// region per block: 64 batches x 98 float2 (= 196 words). Half H of batch bl
// occupies global float2 [bl*98 + H*49, +49). Linear staging index
// lin = k*64 + t -> bl = lin/49, e = lin%49, global off g = lin + (bl+H)*49.
// lin += 64  =>  bl += 1, e += 15, wrap (e>=49): bl += 1 more.
template <int H>
__device__ __forceinline__ void load_half(const float2* __restrict__ X2,
                                          float* __restrict__ xs, int t) {
    int e = (t >= F2PH) ? t - F2PH : t;
    int g = (t >= F2PH) ? t + F2PH * (1 + H) : t + F2PH * H;
    float2 v[F2PH];
#pragma unroll
    for (int k = 0; k < F2PH; ++k) {
        v[k] = X2[g];
        if (k < F2PH - 1) {
            e += 15;
            int w = (e >= F2PH);
            e -= w ? F2PH : 0;
            g += w ? 162 : 113;   // 64 + 49*dbl
        }
    }
#pragma unroll
    for (int k = 0; k < F2PH; ++k)
        reinterpret_cast<float2*>(xs)[k * NT + t] = v[k];  // static imm offs
}

template <int H>
__device__ __forceinline__ void store_half(float2* __restrict__ O2,
                                           const float* __restrict__ xs, int t) {
    float2 v[F2PH];
#pragma unroll
    for (int k = 0; k < F2PH; ++k)
        v[k] = reinterpret_cast<const float2*>(xs)[k * NT + t];
    int e = (t >= F2PH) ? t - F2PH : t;
    int g = (t >= F2PH) ? t + F2PH * (1 + H) : t + F2PH * H;
#pragma unroll
    for (int k = 0; k < F2PH; ++k) {
        O2[g] = v[k];
        if (k < F2PH - 1) {
            e += 15;
            int w = (e >= F2PH);
            e -= w ? F2PH : 0;
            g += w ? 162 : 113;
        }
    }
}

template <int C>
__device__ __forceinline__ void chunk(float* __restrict__ xrow, float r[49],
                                      const float* __restrict__ WQ,
                                      const float* __restrict__ WK,
                                      const float* __restrict__ WV,
                                      const float* __restrict__ Dm) {
    constexpr int CO = (C & 1) * CS;    // col offset within the 14-wide row
    constexpr int RO = (C >> 1) * CS;   // global row offset (for D)
    const float* wq = WQ + C * 49;      // wave-uniform -> s_load
    const float* wk = WK + C * 49;
    const float* wv = WV + C * 49;

    float x[49];
#pragma unroll
    for (int i = 0; i < CS; ++i)
#pragma unroll
        for (int j = 0; j < CS; ++j)
            x[i * CS + j] = xrow[i * 14 + CO + j];

    float K[49], V[49];
#pragma unroll
    for (int j = 0; j < CS; ++j) {
        float wck[CS], wcv[CS];
#pragma unroll
        for (int k = 0; k < CS; ++k) {
            wck[k] = wk[k * CS + j];
            wcv[k] = wv[k * CS + j];
        }
#pragma unroll
        for (int i = 0; i < CS; ++i) {
            float ak = 0.f, av = 0.f;
#pragma unroll
            for (int k = 0; k < CS; ++k) {
                ak = fmaf(x[i * CS + k], wck[k], ak);
                av = fmaf(x[i * CS + k], wcv[k], av);
            }
            K[i * CS + j] = ak;
            V[i * CS + j] = av;
        }
    }

#pragma unroll
    for (int d = 0; d < CS; ++d) {
        const float ev = (d == 0) ? 0.2f : (d == 1) ? 0.04f : (d == 2) ? 0.008f
                        : (d == 3) ? 0.0016f : (d == 4) ? 3.2e-4f
                        : (d == 5) ? 6.4e-5f : 1.28e-5f;
        float q[CS];
#pragma unroll
        for (int j = 0; j < CS; ++j) {
            float a = 0.f;
#pragma unroll
            for (int k = 0; k < CS; ++k)
                a = fmaf(x[d * CS + k], wq[k * CS + j], a);
            q[j] = a;
        }
        float s[CS];
#pragma unroll
        for (int k = 0; k < CS; ++k) {
            float a = 0.f;
#pragma unroll
            for (int j = 0; j < CS; ++j) a = fmaf(q[j], K[k * CS + j], a);
            s[k] = a * Dm[(RO + d) * 14 + CO + k];   // uniform -> s_load
        }
        float o[CS];
#pragma unroll
        for (int v = 0; v < CS; ++v) {
            float a = 0.f;
#pragma unroll
            for (int j = 0; j < CS; ++j) a = fmaf(q[j], r[j * CS + v], a);
            o[v] = ev * a;
        }
#pragma unroll
        for (int k = 0; k < CS; ++k)
#pragma unroll
            for (int v = 0; v < CS; ++v)
                o[v] = fmaf(s[k], V[k * CS + v], o[v]);
#pragma unroll
        for (int v = 0; v < CS; ++v)
            xrow[d * 14 + CO + v] = o[v];   // over dead x slots (in-order DS)
    }

#pragma unroll
    for (int dd = 0; dd < CS; ++dd)
#pragma unroll
        for (int v = 0; v < CS; ++v) {
            float a = r[dd * CS + v];
#pragma unroll
            for (int k = 0; k < CS; ++k)
                a = fmaf(K[k * CS + dd], V[k * CS + v], a);
            r[dd * CS + v] = a;
        }
}

__global__ __launch_bounds__(NT, 2) void retention_kernel(
    const float* __restrict__ X, const float* __restrict__ WQ,
    const float* __restrict__ WK, const float* __restrict__ WV,
    const float* __restrict__ Dm, float* __restrict__ Out) {
    __shared__ float xs[NT * LDSW];   // 25088 B -> 6 blocks/CU
    const int t = threadIdx.x;
    const size_t breg = (size_t)blockIdx.x * (NT * LDSW);  // float2 units
    const float2* X2 = reinterpret_cast<const float2*>(X) + breg;
    float2*       O2 = reinterpret_cast<float2*>(Out) + breg;
    float* xrow = xs + t * LDSW;

    float r[49];
#pragma unroll
    for (int i = 0; i < 49; ++i) r[i] = 0.f;

    load_half<0>(X2, xs, t);
    chunk<0>(xrow, r, WQ, WK, WV, Dm);
    chunk<1>(xrow, r, WQ, WK, WV, Dm);
    store_half<0>(O2, xs, t);

    load_half<1>(X2, xs, t);
    chunk<2>(xrow, r, WQ, WK, WV, Dm);
    chunk<3>(xrow, r, WQ, WK, WV, Dm);
    store_half<1>(O2, xs, t);
}

extern "C" void kernel_launch(void* const* d_in, const int* in_sizes, int n_in,
                              void* d_out, int out_size, void* d_ws, size_t ws_size,
                              hipStream_t stream) {
    const float* X  = (const float*)d_in[0];
    const float* WQ = (const float*)d_in[1];
    const float* WK = (const float*)d_in[2];
    const float* WV = (const float*)d_in[3];
    const float* Dm = (const float*)d_in[4];
    float* Out = (float*)d_out;

    int B = in_sizes[0] / 196;   // 131072, divisible by 64
    int grid = B / NT;
    retention_kernel<<<grid, NT, 0, stream>>>(X, WQ, WK, WV, Dm, Out);
}

// Round 7
// 441.108 us; speedup vs baseline: 1.4317x; 1.0054x over previous
//
#include <hip/hip_runtime.h>

// SimpleRetention R7: B=131072 batches of 14x14 fp32, 4 sequential 7x7
// chunks with carried state r.
// Root-cause theory from R1-R6: the 2x-6x HBM amplification in every round
// was REGISTER-SPILL SCRATCH TRAFFIC (live set >> the 128-VGPR cap the
// compiler chose), not the I/O pattern. R7 therefore:
//  - lifts the cap (amdgpu_waves_per_eu(2,4) -> 256 VGPR budget),
//  - shrinks live set: x stays in LDS, rows read on demand (K,V,r in regs
//    = 147 core), no hand-held staging buffer,
//  - keeps the lane-contiguous float2 staging pattern (R2-proven traffic),
//    fully unrolled so the scheduler batches loads itself,
//  - 1-wave blocks (no barriers; same-wave DS ops are in-order), 25KB LDS
//    -> 6 blocks/CU.

#define CS 7
#define NT 64
#define F2PH 49   // float2 per batch per half
#define LDSW 98   // floats per batch in LDS

// Block region: 64 batches x 98 float2. Half H of batch bl = float2
// [bl*98 + H*49, +49). Staging index lin = k*64 + t -> bl = lin/49,
// e = lin%49, global float2 g = lin + (bl + H)*49.
// lin += 64 => e += 15 (wrap: -49, bl extra +1): g += 113 or 162.
template <int H>
__device__ __forceinline__ void load_half(const float2* __restrict__ X2,
                                          float2* __restrict__ xs2, int t) {
    int e = (t >= F2PH) ? t - F2PH : t;
    int g = (t >= F2PH) ? t + F2PH * (1 + H) : t + F2PH * H;
#pragma unroll
    for (int k = 0; k < F2PH; ++k) {
        xs2[k * NT + t] = X2[g];    // load feeds ds_write; scheduler batches
        if (k < F2PH - 1) {
            e += 15;
            int w = (e >= F2PH);
            e -= w ? F2PH : 0;
            g += w ? 162 : 113;
        }
    }
}

template <int H>
__device__ __forceinline__ void store_half(float2* __restrict__ O2,
                                           const float2* __restrict__ xs2,
                                           int t) {
    int e = (t >= F2PH) ? t - F2PH : t;
    int g = (t >= F2PH) ? t + F2PH * (1 + H) : t + F2PH * H;
#pragma unroll
    for (int k = 0; k < F2PH; ++k) {
        O2[g] = xs2[k * NT + t];
        if (k < F2PH - 1) {
            e += 15;
            int w = (e >= F2PH);
            e -= w ? F2PH : 0;
            g += w ? 162 : 113;
        }
    }
}

template <int C>
__device__ __forceinline__ void chunk(float* __restrict__ xrow, float r[49],
                                      const float* __restrict__ WQ,
                                      const float* __restrict__ WK,
                                      const float* __restrict__ WV,
                                      const float* __restrict__ Dm) {
    constexpr int CO = (C & 1) * CS;    // col offset within 14-wide row
    constexpr int RO = (C >> 1) * CS;   // global row offset (for D)
    const float* wq = WQ + C * 49;      // wave-uniform -> s_load
    const float* wk = WK + C * 49;
    const float* wv = WV + C * 49;

    // K,V row-by-row from LDS x rows (x never fully register-resident)
    float K[49], V[49];
#pragma unroll
    for (int i = 0; i < CS; ++i) {
        float xr[CS];
#pragma unroll
        for (int k = 0; k < CS; ++k) xr[k] = xrow[i * 14 + CO + k];
#pragma unroll
        for (int j = 0; j < CS; ++j) {
            float ak = 0.f, av = 0.f;
#pragma unroll
            for (int k = 0; k < CS; ++k) {
                ak = fmaf(xr[k], wk[k * CS + j], ak);
                av = fmaf(xr[k], wv[k * CS + j], av);
            }
            K[i * CS + j] = ak;
            V[i * CS + j] = av;
        }
    }

    // per output row d: q (x row d re-read from LDS) -> s -> cross -> o
#pragma unroll
    for (int d = 0; d < CS; ++d) {
        const float ev = (d == 0) ? 0.2f : (d == 1) ? 0.04f : (d == 2) ? 0.008f
                        : (d == 3) ? 0.0016f : (d == 4) ? 3.2e-4f
                        : (d == 5) ? 6.4e-5f : 1.28e-5f;
        float xr[CS];
#pragma unroll
        for (int k = 0; k < CS; ++k) xr[k] = xrow[d * 14 + CO + k];
        float q[CS];
#pragma unroll
        for (int j = 0; j < CS; ++j) {
            float a = 0.f;
#pragma unroll
            for (int k = 0; k < CS; ++k)
                a = fmaf(xr[k], wq[k * CS + j], a);
            q[j] = a;
        }
        float s[CS];
#pragma unroll
        for (int k = 0; k < CS; ++k) {
            float a = 0.f;
#pragma unroll
            for (int j = 0; j < CS; ++j) a = fmaf(q[j], K[k * CS + j], a);
            s[k] = a * Dm[(RO + d) * 14 + CO + k];   // uniform -> s_load
        }
        float o[CS];
#pragma unroll
        for (int v = 0; v < CS; ++v) {
            float a = 0.f;
#pragma unroll
            for (int j = 0; j < CS; ++j) a = fmaf(q[j], r[j * CS + v], a);
            o[v] = ev * a;
        }
#pragma unroll
        for (int k = 0; k < CS; ++k)
#pragma unroll
            for (int v = 0; v < CS; ++v)
                o[v] = fmaf(s[k], V[k * CS + v], o[v]);
        // overwrite own-column slots of x row d (dead for this chunk; the
        // sibling chunk uses the other 7 columns)
#pragma unroll
        for (int v = 0; v < CS; ++v)
            xrow[d * 14 + CO + v] = o[v];
    }

    // r += K^T V
#pragma unroll
    for (int dd = 0; dd < CS; ++dd)
#pragma unroll
        for (int v = 0; v < CS; ++v) {
            float a = r[dd * CS + v];
#pragma unroll
            for (int k = 0; k < CS; ++k)
                a = fmaf(K[k * CS + dd], V[k * CS + v], a);
            r[dd * CS + v] = a;
        }
}

__global__ __launch_bounds__(NT)
__attribute__((amdgpu_waves_per_eu(2, 4)))
void retention_kernel(const float* __restrict__ X,
                      const float* __restrict__ WQ,
                      const float* __restrict__ WK,
                      const float* __restrict__ WV,
                      const float* __restrict__ Dm,
                      float* __restrict__ Out) {
    __shared__ float xs[NT * LDSW];   // 25088 B -> 6 blocks/CU
    const int t = threadIdx.x;
    const size_t breg = (size_t)blockIdx.x * (NT * F2PH * 2);  // float2 units
    const float2* X2 = reinterpret_cast<const float2*>(X) + breg;
    float2*       O2 = reinterpret_cast<float2*>(Out) + breg;
    float2* xs2 = reinterpret_cast<float2*>(xs);
    float* xrow = xs + t * LDSW;

    float r[49];
#pragma unroll
    for (int i = 0; i < 49; ++i) r[i] = 0.f;

    load_half<0>(X2, xs2, t);
    chunk<0>(xrow, r, WQ, WK, WV, Dm);
    chunk<1>(xrow, r, WQ, WK, WV, Dm);
    store_half<0>(O2, xs2, t);

    load_half<1>(X2, xs2, t);
    chunk<2>(xrow, r, WQ, WK, WV, Dm);
    chunk<3>(xrow, r, WQ, WK, WV, Dm);
    store_half<1>(O2, xs2, t);
}

extern "C" void kernel_launch(void* const* d_in, const int* in_sizes, int n_in,
                              void* d_out, int out_size, void* d_ws, size_t ws_size,
                              hipStream_t stream) {
    const float* X  = (const float*)d_in[0];
    const float* WQ = (const float*)d_in[1];
    const float* WK = (const float*)d_in[2];
    const float* WV = (const float*)d_in[3];
    const float* Dm = (const float*)d_in[4];
    float* Out = (float*)d_out;

    int B = in_sizes[0] / 196;   // 131072, divisible by 64
    int grid = B / NT;
    retention_kernel<<<grid, NT, 0, stream>>>(X, WQ, WK, WV, Dm, Out);
}